// Round 8
// baseline (1266.908 us; speedup 1.0000x reference)
//
#include <hip/hip_runtime.h>
#include <hip/hip_bf16.h>
#include <math.h>

// GGNN: N=50000 nodes, E=400000 edges, G=64 graphs, IN=64, OUT=128, 4 etypes, 8 steps.
// R13: fused per-step kernel (agg + gates + GRU) for producer/consumer overlap.
//   Evidence: agg is pinned at FETCH 41MB / ~600GB/s (~85us) across 3 different gather
//   structures (R6/R11/R12) -> scattered-fetch bound, bytes irreducible. Gates (49us,
//   MFMA-bound) previously ran AFTER it; fused, co-resident blocks in different phases
//   overlap memory (gather) with compute (gates MFMA).
//   - hb double-buffered [2][N][128] fp16: step s gathers from hb[s&1] (all written
//     last step -> no race), GRU writes hb[(s+1)&1]. h stays fp32 master.
//   - ab never goes to global: agg epilogue writes fp16 into gates A-tile (LDS).
//   - LDS 51.7KB (Sh 34.8 aliased by Bs + As 16.9) -> 3 blocks/CU; biases read from L2.
//   - gather = R11 flat predicated walk (best measured); gates = R11 6-chunk LDS-staged.

#define NN 50000
#define NE 400000
#define NG 64
#define IND 64
#define OD 128
#define NN4 (NN * 4)
#define RC 8      // readout chunks per graph

typedef _Float16 f16x8 __attribute__((ext_vector_type(8)));
typedef _Float16 f16x4 __attribute__((ext_vector_type(4)));
typedef _Float16 f16x2 __attribute__((ext_vector_type(2)));
typedef float f32x4 __attribute__((ext_vector_type(4)));

__device__ inline unsigned short f2h(float x) {
    _Float16 hv = (_Float16)x;
    unsigned short u;
    __builtin_memcpy(&u, &hv, 2);
    return u;
}

// ---------------- Ws fp32 -> concatenated fp16 Wcat[o][t*128+k] ----------------
__global__ void k_cvtws(const float* __restrict__ Ws, unsigned short* __restrict__ Wcat) {
    int i = blockIdx.x * 256 + threadIdx.x;   // 65536
    if (i >= 65536) return;
    int o = i >> 9, col = i & 511;
    int t = col >> 7, k = col & 127;
    Wcat[i] = f2h(Ws[t * 16384 + o * 128 + k]);
}

// ---------------- pack GRU weights into 6 stage-chunks of 128x128 fp16 ----------------
// chunk c: rows (c>>1)*128..+128 of (c&1 ? W_hh : W_ih)
//   c0=R_ih c1=R_hh c2=Z_ih c3=Z_hh c4=IN_ih c5=HN_hh
// bpk[0..255] = b_ih+b_hh (r,z), bpk[256..383] = b_ih[256..], bpk[384..511] = b_hh[256..]
__global__ void k_pack(const float* __restrict__ Wih, const float* __restrict__ Whh,
                       const float* __restrict__ bih, const float* __restrict__ bhh,
                       unsigned short* __restrict__ Wpk, float* __restrict__ bpk) {
    int i = blockIdx.x * 256 + threadIdx.x;
    if (i < 98304) {
        int c = i >> 14, j = i & 16383, o = j >> 7, k = j & 127;
        const float* W = (c & 1) ? Whh : Wih;
        Wpk[i] = f2h(W[((c >> 1) * 128 + o) * 128 + k]);
    }
    if (i < 512) {
        float b;
        if (i < 256) b = bih[i] + bhh[i];
        else if (i < 384) b = bih[i];
        else b = bhh[i - 128];
        bpk[i] = b;
    }
}

// ---------------- init h = [node_features | 0] (fp32 + fp16 shadow hb0) --------------
__global__ void k_init_h(const float* __restrict__ nf, float* __restrict__ h,
                         unsigned short* __restrict__ hb0) {
    int i = blockIdx.x * 256 + threadIdx.x;
    if (i >= NN * OD) return;
    int n = i >> 7, d = i & 127;
    float v = (d < IND) ? nf[n * IND + d] : 0.f;
    h[i] = v;
    hb0[i] = f2h(v);
}

// ---------------- (dst, etype) CSR build: 200000 segments ----------------
__global__ void k_count(const int* __restrict__ dst, const int* __restrict__ et,
                        int* __restrict__ deg4) {
    int e = blockIdx.x * 256 + threadIdx.x;
    if (e < NE) atomicAdd(&deg4[dst[e] * 4 + et[e]], 1);
}

__global__ void k_scan1(const int* __restrict__ deg, int* __restrict__ rowp,
                        int* __restrict__ bsum, int n) {
    __shared__ int buf[1024];
    int tid = threadIdx.x;
    int i = blockIdx.x * 1024 + tid;
    int v = (i < n) ? deg[i] : 0;
    buf[tid] = v;
    __syncthreads();
    for (int off = 1; off < 1024; off <<= 1) {
        int t = (tid >= off) ? buf[tid - off] : 0;
        __syncthreads();
        buf[tid] += t;
        __syncthreads();
    }
    if (i < n) rowp[i + 1] = buf[tid];
    if (tid == 1023) bsum[blockIdx.x] = buf[tid];
}

__global__ void k_scan2(int* __restrict__ bsum, int nb) {
    __shared__ int buf[256];
    int tid = threadIdx.x;
    int v = (tid < nb) ? bsum[tid] : 0;
    buf[tid] = v;
    __syncthreads();
    for (int off = 1; off < 256; off <<= 1) {
        int t = (tid >= off) ? buf[tid - off] : 0;
        __syncthreads();
        buf[tid] += t;
        __syncthreads();
    }
    if (tid < nb) bsum[tid] = buf[tid] - v;   // exclusive
}

__global__ void k_scan3(const int* __restrict__ deg, const int* __restrict__ bsum,
                        int* __restrict__ rowp, int* __restrict__ cursor, int n) {
    int i = blockIdx.x * 256 + threadIdx.x;
    if (i >= n) return;
    int incl = rowp[i + 1] + bsum[i >> 10];
    rowp[i + 1] = incl;
    cursor[i] = incl - deg[i];
    if (i == 0) rowp[0] = 0;
}

__global__ void k_fill(const int* __restrict__ src, const int* __restrict__ dst,
                       const int* __restrict__ et, int* __restrict__ cursor,
                       int* __restrict__ epk) {
    int e = blockIdx.x * 256 + threadIdx.x;
    if (e < NE) {
        int t = et[e];
        int pos = atomicAdd(&cursor[dst[e] * 4 + t], 1);
        epk[pos] = src[e] | (t << 16);     // src < 2^16, et 2 bits
    }
}

// ---------------- graph CSR build (by graph id), for readout ----------------
__global__ void k_gcount(const int* __restrict__ gid, int* __restrict__ gdeg) {
    __shared__ int c[NG];
    int tid = threadIdx.x;
    if (tid < NG) c[tid] = 0;
    __syncthreads();
    int n = blockIdx.x * 1024 + tid;
    if (n < NN) atomicAdd(&c[gid[n]], 1);
    __syncthreads();
    if (tid < NG && c[tid] > 0) atomicAdd(&gdeg[tid], c[tid]);
}

__global__ void k_gscan(const int* __restrict__ gdeg, int* __restrict__ growp,
                        int* __restrict__ gcur) {
    __shared__ int buf[NG];
    int tid = threadIdx.x;
    int v = gdeg[tid];
    buf[tid] = v;
    __syncthreads();
    for (int off = 1; off < NG; off <<= 1) {
        int t = (tid >= off) ? buf[tid - off] : 0;
        __syncthreads();
        buf[tid] += t;
        __syncthreads();
    }
    growp[tid + 1] = buf[tid];
    gcur[tid] = buf[tid] - v;
    if (tid == 0) growp[0] = 0;
}

__global__ void k_gfill(const int* __restrict__ gid, int* __restrict__ gcur,
                        int* __restrict__ nlist) {
    __shared__ int lcnt[NG];
    __shared__ int lbase[NG];
    int tid = threadIdx.x;
    if (tid < NG) lcnt[tid] = 0;
    __syncthreads();
    int n = blockIdx.x * 1024 + tid;
    int g = -1, rank = 0;
    if (n < NN) { g = gid[n]; rank = atomicAdd(&lcnt[g], 1); }
    __syncthreads();
    if (tid < NG && lcnt[tid] > 0) lbase[tid] = atomicAdd(&gcur[tid], lcnt[tid]);
    __syncthreads();
    if (n < NN) nlist[lbase[g] + rank] = n;
}

// ---------------- fused step: gather -> agg MFMA -> gates MFMA -> GRU ----------------
// 256 thr (4 waves), 32 rows/tile (grid 1563), 51.7KB LDS -> 3 blocks/CU.
// Phase 1 (gather): 8 thr/row, 16 dims; flat predicated walk over epk (R11).
// Phase 2 (agg MFMA): K=512 vs Wcat (L2), + cnt*bs epilogue -> ab into As LDS (fp16).
// Phase 3 (gates): 6 weight chunks staged to Bs (aliases Sh); accR/Z/I/H in regs.
// Phase 4 (GRU): in-register, write h fp32 + hb_next fp16.
__global__ __launch_bounds__(256) void k_step(
    const unsigned short* __restrict__ hbc,   // hb current [N][128] fp16
    unsigned short* __restrict__ hbn,         // hb next
    float* __restrict__ h,
    const int* __restrict__ rowp4, const int* __restrict__ epk,
    const int* __restrict__ deg4,
    const unsigned short* __restrict__ Wcat,  // 128 x 512 fp16
    const float* __restrict__ bs,             // 512 fp32
    const unsigned short* __restrict__ Wpk,   // 6 chunks of 128x128 fp16
    const float* __restrict__ bpk) {          // 512 packed biases
    __shared__ unsigned short Sh[4 * 32 * 136];   // 34816 B s-planes; aliased by Bs
    __shared__ unsigned short As[32 * 264];       // 16896 B gates A-tile [ab|hb]

    const int tid = threadIdx.x;
    const int m0 = blockIdx.x * 32;

    // stage own-tile hb into As cols 128..255 (coalesced; used in phase 3)
    {
        const uint4* Hb4 = (const uint4*)hbc;    // 16 uint4 per 128-half row
#pragma unroll
        for (int it = 0; it < 2; ++it) {
            int i = tid + it * 256;              // 0..511
            int row = i >> 4, qq = i & 15;
            int nn = m0 + row;
            uint4 v = (nn < NN) ? Hb4[(size_t)nn * 16 + qq] : make_uint4(0u, 0u, 0u, 0u);
            *(uint4*)&As[row * 264 + 128 + qq * 8] = v;
        }
    }

    // ---- phase 1: gather (flat predicated walk, 8 thr/row x 16 dims) ----
    const int r = tid >> 3;
    const int sl = tid & 7;
    const int d0 = sl * 16;
    const int n = m0 + r;

    float a0[16], a1[16], a2[16], a3[16];
#pragma unroll
    for (int k = 0; k < 16; ++k) { a0[k] = 0.f; a1[k] = 0.f; a2[k] = 0.f; a3[k] = 0.f; }

    if (n < NN) {
        int i = rowp4[n * 4], end = rowp4[n * 4 + 4];
        for (; i + 2 <= end; i += 2) {
            int p0 = epk[i], p1 = epk[i + 1];
            const f16x8* r0 = (const f16x8*)&hbc[(size_t)(p0 & 0xFFFF) * 128 + d0];
            const f16x8* r1 = (const f16x8*)&hbc[(size_t)(p1 & 0xFFFF) * 128 + d0];
            f16x8 u0 = r0[0], u1 = r0[1];
            f16x8 v0 = r1[0], v1 = r1[1];
            int e0 = p0 >> 16, e1 = p1 >> 16;
#pragma unroll
            for (int k = 0; k < 8; ++k) {
                float f0 = (float)u0[k], f1 = (float)u1[k];
                float g0 = (float)v0[k], g1 = (float)v1[k];
                a0[k]     += (e0 == 0 ? f0 : 0.f) + (e1 == 0 ? g0 : 0.f);
                a0[8 + k] += (e0 == 0 ? f1 : 0.f) + (e1 == 0 ? g1 : 0.f);
                a1[k]     += (e0 == 1 ? f0 : 0.f) + (e1 == 1 ? g0 : 0.f);
                a1[8 + k] += (e0 == 1 ? f1 : 0.f) + (e1 == 1 ? g1 : 0.f);
                a2[k]     += (e0 == 2 ? f0 : 0.f) + (e1 == 2 ? g0 : 0.f);
                a2[8 + k] += (e0 == 2 ? f1 : 0.f) + (e1 == 2 ? g1 : 0.f);
                a3[k]     += (e0 == 3 ? f0 : 0.f) + (e1 == 3 ? g0 : 0.f);
                a3[8 + k] += (e0 == 3 ? f1 : 0.f) + (e1 == 3 ? g1 : 0.f);
            }
        }
        if (i < end) {
            int p0 = epk[i];
            const f16x8* r0 = (const f16x8*)&hbc[(size_t)(p0 & 0xFFFF) * 128 + d0];
            f16x8 u0 = r0[0], u1 = r0[1];
            int e0 = p0 >> 16;
#pragma unroll
            for (int k = 0; k < 8; ++k) {
                float f0 = (float)u0[k], f1 = (float)u1[k];
                a0[k] += (e0 == 0 ? f0 : 0.f); a0[8 + k] += (e0 == 0 ? f1 : 0.f);
                a1[k] += (e0 == 1 ? f0 : 0.f); a1[8 + k] += (e0 == 1 ? f1 : 0.f);
                a2[k] += (e0 == 2 ? f0 : 0.f); a2[8 + k] += (e0 == 2 ? f1 : 0.f);
                a3[k] += (e0 == 3 ? f0 : 0.f); a3[8 + k] += (e0 == 3 ? f1 : 0.f);
            }
        }
    }

    // write per-etype s-planes (unguarded: zero rows for n>=NN)
    {
        f16x8 w0, w1;
#pragma unroll
        for (int k = 0; k < 8; ++k) { w0[k] = (_Float16)a0[k]; w1[k] = (_Float16)a0[8 + k]; }
        *(f16x8*)&Sh[0 * 4352 + r * 136 + d0] = w0; *(f16x8*)&Sh[0 * 4352 + r * 136 + d0 + 8] = w1;
#pragma unroll
        for (int k = 0; k < 8; ++k) { w0[k] = (_Float16)a1[k]; w1[k] = (_Float16)a1[8 + k]; }
        *(f16x8*)&Sh[1 * 4352 + r * 136 + d0] = w0; *(f16x8*)&Sh[1 * 4352 + r * 136 + d0 + 8] = w1;
#pragma unroll
        for (int k = 0; k < 8; ++k) { w0[k] = (_Float16)a2[k]; w1[k] = (_Float16)a2[8 + k]; }
        *(f16x8*)&Sh[2 * 4352 + r * 136 + d0] = w0; *(f16x8*)&Sh[2 * 4352 + r * 136 + d0 + 8] = w1;
#pragma unroll
        for (int k = 0; k < 8; ++k) { w0[k] = (_Float16)a3[k]; w1[k] = (_Float16)a3[8 + k]; }
        *(f16x8*)&Sh[3 * 4352 + r * 136 + d0] = w0; *(f16x8*)&Sh[3 * 4352 + r * 136 + d0 + 8] = w1;
    }
    __syncthreads();

    // ---- phase 2: agg MFMA (K=512, B from Wcat in L2), epilogue -> As ab cols ----
    const int lane = tid & 63;
    const int w = tid >> 6;
    const int lr = lane & 15;
    const int q = lane >> 4;
    const int rt = w & 1;         // row-tile 0..1
    const int cts = (w >> 1) * 4; // col-tile base 0 or 4

    {
        f32x4 acc[4];
#pragma unroll
        for (int j = 0; j < 4; ++j) acc[j] = (f32x4){0.f, 0.f, 0.f, 0.f};

#pragma unroll
        for (int ks = 0; ks < 16; ++ks) {
            int t = ks >> 2, ksl = ks & 3;
            f16x8 af = *(const f16x8*)&Sh[t * 4352 + (rt * 16 + lr) * 136 + ksl * 32 + q * 8];
#pragma unroll
            for (int j = 0; j < 4; ++j) {
                f16x8 bf = *(const f16x8*)&Wcat[((cts + j) * 16 + lr) * 512 + ks * 32 + q * 8];
                acc[j] = __builtin_amdgcn_mfma_f32_16x16x32_f16(af, bf, acc[j], 0, 0, 0);
            }
        }

        int rowb = rt * 16 + q * 4;   // local row base
#pragma unroll
        for (int rr = 0; rr < 4; ++rr) {
            int rl = rowb + rr;
            int n2 = m0 + rl;
            if (n2 < NN) {
                int4 c = *(const int4*)&deg4[n2 * 4];
#pragma unroll
                for (int j = 0; j < 4; ++j) {
                    int col = (cts + j) * 16 + lr;
                    float v = acc[j][rr]
                            + c.x * bs[col] + c.y * bs[128 + col]
                            + c.z * bs[256 + col] + c.w * bs[384 + col];
                    As[rl * 264 + col] = f2h(v);
                }
            } else {
#pragma unroll
                for (int j = 0; j < 4; ++j)
                    As[rl * 264 + (cts + j) * 16 + lr] = 0;
            }
        }
    }

    // ---- phase 3: gates (Bs aliases Sh) ----
    unsigned short* Bs = Sh;
    const uint4* W4 = (const uint4*)Wpk;

    f32x4 accR[4], accZ[4], accI[4], accH[4];
#pragma unroll
    for (int j = 0; j < 4; ++j) {
        accR[j] = (f32x4){0.f, 0.f, 0.f, 0.f};
        accZ[j] = (f32x4){0.f, 0.f, 0.f, 0.f};
        accI[j] = (f32x4){0.f, 0.f, 0.f, 0.f};
        accH[j] = (f32x4){0.f, 0.f, 0.f, 0.f};
    }

#define GCHUNK(C, ACC)                                                              \
    __syncthreads();                                                                \
    _Pragma("unroll")                                                               \
    for (int it = 0; it < 8; ++it) {                                                \
        int i = tid + it * 256;                                                     \
        *(uint4*)&Bs[(i >> 4) * 136 + (i & 15) * 8] = W4[(C) * 2048 + i];           \
    }                                                                               \
    __syncthreads();                                                                \
    _Pragma("unroll")                                                               \
    for (int ks = 0; ks < 4; ++ks) {                                                \
        f16x8 af = *(const f16x8*)&As[(rt * 16 + lr) * 264 + ((C) & 1) * 128        \
                                      + ks * 32 + q * 8];                           \
        _Pragma("unroll")                                                           \
        for (int j = 0; j < 4; ++j) {                                               \
            f16x8 bf = *(const f16x8*)&Bs[((cts + j) * 16 + lr) * 136               \
                                          + ks * 32 + q * 8];                       \
            ACC[j] = __builtin_amdgcn_mfma_f32_16x16x32_f16(af, bf, ACC[j], 0, 0, 0); \
        }                                                                           \
    }

    GCHUNK(0, accR)   // R  += ab . W_ih_r
    GCHUNK(1, accR)   // R  += hb . W_hh_r
    GCHUNK(2, accZ)   // Z  += ab . W_ih_z
    GCHUNK(3, accZ)   // Z  += hb . W_hh_z
    GCHUNK(4, accI)   // IN  = ab . W_ih_n
    GCHUNK(5, accH)   // HN  = hb . W_hh_n
#undef GCHUNK

    // ---- phase 4: GRU in-register, write h fp32 + hb_next fp16 ----
    int rowb = m0 + rt * 16 + q * 4;
#pragma unroll
    for (int rr = 0; rr < 4; ++rr) {
        int n2 = rowb + rr;
        if (n2 < NN) {
            float* hrow = h + (size_t)n2 * OD;
            unsigned short* hbrow = hbn + (size_t)n2 * OD;
#pragma unroll
            for (int j = 0; j < 4; ++j) {
                int col = (cts + j) * 16 + lr;
                float R = 1.f / (1.f + __expf(-(accR[j][rr] + bpk[col])));
                float Z = 1.f / (1.f + __expf(-(accZ[j][rr] + bpk[128 + col])));
                float NV = tanhf(accI[j][rr] + bpk[256 + col]
                                 + R * (accH[j][rr] + bpk[384 + col]));
                float hold = hrow[col];
                float hnew = (1.f - Z) * NV + Z * hold;
                hrow[col] = hnew;
                hbrow[col] = f2h(hnew);
            }
        }
    }
}

// ---------------- graph readout: register acc over graph-sorted node list ------------
__global__ void k_readout(const float* __restrict__ h, const float* __restrict__ nf,
                          const int* __restrict__ nlist, const int* __restrict__ growp,
                          float* __restrict__ partial) {
    int g = blockIdx.x >> 3, c = blockIdx.x & (RC - 1);
    int d = threadIdx.x;
    int s = growp[g], e = growp[g + 1], len = e - s;
    int i0 = s + (int)((long long)len * c / RC);
    int i1 = s + (int)((long long)len * (c + 1) / RC);
    float acc = 0.f;
    for (int i = i0; i < i1; ++i) {
        int n = nlist[i];
        acc += (d < OD) ? h[(size_t)n * OD + d] : nf[(size_t)n * IND + (d - OD)];
    }
    partial[(size_t)blockIdx.x * 192 + d] = acc;
}

__global__ void k_reduce(const float* __restrict__ partial, float* __restrict__ feats) {
    int i = blockIdx.x * 256 + threadIdx.x;
    if (i >= NG * 192) return;
    int g = i / 192, d = i % 192;
    float s = 0.f;
    for (int c = 0; c < RC; ++c) s += partial[(size_t)(g * RC + c) * 192 + d];
    feats[i] = s;
}

__global__ void k_final(const float* __restrict__ feats, const float* __restrict__ W_cls,
                        const float* __restrict__ b_cls, float* __restrict__ out) {
    int g = threadIdx.x;
    if (g >= NG) return;
    float acc = b_cls[0];
    for (int d = 0; d < 192; ++d) acc += feats[g * 192 + d] * W_cls[d];
    out[g] = 1.f / (1.f + __expf(-acc));
}

extern "C" void kernel_launch(void* const* d_in, const int* in_sizes, int n_in,
                              void* d_out, int out_size, void* d_ws, size_t ws_size,
                              hipStream_t stream) {
    const float* nf    = (const float*)d_in[0];
    const int*   src   = (const int*)d_in[1];
    const int*   dst   = (const int*)d_in[2];
    const int*   et    = (const int*)d_in[3];
    const int*   gid   = (const int*)d_in[4];
    const float* Ws    = (const float*)d_in[5];
    const float* bs    = (const float*)d_in[6];
    const float* W_ih  = (const float*)d_in[7];
    const float* W_hh  = (const float*)d_in[8];
    const float* b_ih  = (const float*)d_in[9];
    const float* b_hh  = (const float*)d_in[10];
    const float* W_cls = (const float*)d_in[11];
    const float* b_cls = (const float*)d_in[12];
    float* out = (float*)d_out;

    char* ws = (char*)d_ws;
    size_t off = 0;
    auto alloc = [&](size_t bytes) -> void* {
        off = (off + 255) & ~(size_t)255;
        void* p = ws + off;
        off += bytes;
        return p;
    };
    float*          h    = (float*)alloc((size_t)NN * OD * 4);              // 25.6 MB
    unsigned short* hb0  = (unsigned short*)alloc((size_t)NN * OD * 2);     // 12.8 MB
    unsigned short* hb1  = (unsigned short*)alloc((size_t)NN * OD * 2);     // 12.8 MB
    int*   deg4    = (int*)alloc((size_t)NN4 * 4);
    int*   rowp4   = (int*)alloc((size_t)(NN4 + 1) * 4);
    int*   cursor4 = (int*)alloc((size_t)NN4 * 4);
    int*   epk     = (int*)alloc((size_t)NE * 4);
    int*   bsum    = (int*)alloc(256 * 4);
    int*   gdeg    = (int*)alloc(NG * 4);
    int*   growp   = (int*)alloc((NG + 1) * 4);
    int*   gcur    = (int*)alloc(NG * 4);
    int*   nlist   = (int*)alloc((size_t)NN * 4);
    float* feats   = (float*)alloc((size_t)NG * 192 * 4);
    float* partial = (float*)alloc((size_t)NG * RC * 192 * 4);              // 393 KB
    unsigned short* Wcat = (unsigned short*)alloc((size_t)65536 * 2);       // 128 KB
    unsigned short* Wpk  = (unsigned short*)alloc((size_t)98304 * 2);       // 192 KB
    float*          bpk  = (float*)alloc(512 * 4);
    (void)ws_size; (void)in_sizes; (void)n_in; (void)out_size;

    hipMemsetAsync(deg4, 0, (size_t)NN4 * 4, stream);
    hipMemsetAsync(gdeg, 0, NG * 4, stream);

    k_cvtws<<<(65536 + 255) / 256, 256, 0, stream>>>(Ws, Wcat);
    k_pack<<<(98304 + 255) / 256, 256, 0, stream>>>(W_ih, W_hh, b_ih, b_hh, Wpk, bpk);

    k_init_h<<<(NN * OD + 255) / 256, 256, 0, stream>>>(nf, h, hb0);

    // (dst, etype) CSR
    k_count<<<(NE + 255) / 256, 256, 0, stream>>>(dst, et, deg4);
    const int nb4 = (NN4 + 1023) / 1024;   // 196
    k_scan1<<<nb4, 1024, 0, stream>>>(deg4, rowp4, bsum, NN4);
    k_scan2<<<1, 256, 0, stream>>>(bsum, nb4);
    k_scan3<<<(NN4 + 255) / 256, 256, 0, stream>>>(deg4, bsum, rowp4, cursor4, NN4);
    k_fill<<<(NE + 255) / 256, 256, 0, stream>>>(src, dst, et, cursor4, epk);

    // graph CSR (readout)
    const int nbn = (NN + 1023) / 1024;    // 49
    k_gcount<<<nbn, 1024, 0, stream>>>(gid, gdeg);
    k_gscan<<<1, NG, 0, stream>>>(gdeg, growp, gcur);
    k_gfill<<<nbn, 1024, 0, stream>>>(gid, gcur, nlist);

    const int mt32 = (NN + 31) / 32;   // 1563 node tiles
    unsigned short* hbs[2] = {hb0, hb1};
    for (int s = 0; s < 8; ++s) {
        k_step<<<mt32, 256, 0, stream>>>(hbs[s & 1], hbs[(s + 1) & 1], h,
                                         rowp4, epk, deg4, Wcat, bs, Wpk, bpk);
    }

    k_readout<<<NG * RC, 192, 0, stream>>>(h, nf, nlist, growp, partial);
    k_reduce<<<(NG * 192 + 255) / 256, 256, 0, stream>>>(partial, feats);
    k_final<<<1, 64, 0, stream>>>(feats, W_cls, b_cls, out);
}